// Round 14
// baseline (390.465 us; speedup 1.0000x reference)
//
#include <hip/hip_runtime.h>
#include <cmath>

typedef _Float16 f16;
typedef _Float16 f16x8 __attribute__((ext_vector_type(8)));
typedef _Float16 f16x4 __attribute__((ext_vector_type(4)));
typedef __fp16 fp16x2 __attribute__((ext_vector_type(2)));
typedef float f32x4 __attribute__((ext_vector_type(4)));
typedef float f32x16 __attribute__((ext_vector_type(16)));
typedef unsigned int u32;
typedef unsigned int u32x2 __attribute__((ext_vector_type(2)));
typedef unsigned int u32x4 __attribute__((ext_vector_type(4)));

#define MFMA16(a, b, c) __builtin_amdgcn_mfma_f32_16x16x32_f16(a, b, c, 0, 0, 0)
#define MFMA32(a, b, c) __builtin_amdgcn_mfma_f32_32x32x16_f16(a, b, c, 0, 0, 0)
#define Z16 ((f32x16){0.f,0.f,0.f,0.f,0.f,0.f,0.f,0.f,0.f,0.f,0.f,0.f,0.f,0.f,0.f,0.f})
#define EX2(x) __builtin_amdgcn_exp2f(x)

__device__ __forceinline__ void gl2lds16(const f16* g, f16* l) {
    __builtin_amdgcn_global_load_lds(
        (const __attribute__((address_space(1))) unsigned int*)g,
        (__attribute__((address_space(3))) unsigned int*)l, 16, 0, 0);
}

__device__ __forceinline__ u32 pkz(float x, float y) {
    fp16x2 h = __builtin_amdgcn_cvt_pkrtz(x, y);
    return __builtin_bit_cast(u32, h);
}
__device__ __forceinline__ float fswapsum(float x) {
    u32 a = __builtin_bit_cast(u32, x), b;
    asm volatile("v_mov_b32 %0, %1" : "=&v"(b) : "v"(a));
    asm volatile("v_permlane32_swap_b32 %0, %1" : "+v"(a), "+v"(b));
    return __builtin_bit_cast(float, a) + __builtin_bit_cast(float, b);
}
__device__ __forceinline__ float fswapmax(float x) {
    u32 a = __builtin_bit_cast(u32, x), b;
    asm volatile("v_mov_b32 %0, %1" : "=&v"(b) : "v"(a));
    asm volatile("v_permlane32_swap_b32 %0, %1" : "+v"(a), "+v"(b));
    return fmaxf(__builtin_bit_cast(float, a), __builtin_bit_cast(float, b));
}
#define MAX3(a, b, c) fmaxf(fmaxf((a), (b)), (c))

// ---------------- merged f32 -> f16 convert for all 6 inputs ----------------
__global__ __launch_bounds__(256) void cvt_all(
    const float* __restrict__ hs, const float* __restrict__ es,
    const float* __restrict__ Wq, const float* __restrict__ Wk,
    const float* __restrict__ Wv, const float* __restrict__ Wo,
    f16* __restrict__ dst)
{
    const int c = blockIdx.x * 256 + threadIdx.x;
    const float* src; int off;
    if (c < 2097152) { src = (c < 1048576) ? hs : es; off = c & 1048575; }
    else {
        const int cc = c - 2097152;
        const int wsel = cc >> 19; off = cc & 524287;
        src = wsel == 0 ? Wq : wsel == 1 ? Wk : wsel == 2 ? Wv : Wo;
    }
    const float4* p = (const float4*)src + (size_t)off * 2;
    const float4 a = p[0], b2 = p[1];
    f16x8 o = {(f16)a.x, (f16)a.y, (f16)a.z, (f16)a.w,
               (f16)b2.x, (f16)b2.y, (f16)b2.z, (f16)b2.w};
    *(f16x8*)(dst + (size_t)c * 8) = o;
}

// ---------------- fused Q+K+V GEMM: 256x256 tiles, BK=64, 8-phase counted-vmcnt ----------------
// 384 blocks: [0,128) Q = hs@Wq^T (+RoPE), [128,256) K = es@Wk^T (+RoPE),
// [256,384) V^T = Wv@es^T (transposed write). All K-dim = 2048, f16 MFMA.
__global__ __launch_bounds__(512, 2) void qkv256(
    const f16* __restrict__ hs, const f16* __restrict__ es,
    const f16* __restrict__ Wq, const f16* __restrict__ Wk, const f16* __restrict__ Wv,
    f16* __restrict__ Qo, f16* __restrict__ Ko, f16* __restrict__ Vo,
    const float* __restrict__ cq, const float* __restrict__ sq,
    const float* __restrict__ ck, const float* __restrict__ sk)
{
    __shared__ __align__(16) f16 LA[2][2][128 * 64];   // [dbuf][half][row*64+col]
    __shared__ __align__(16) f16 LB[2][2][128 * 64];

    const int tid = threadIdx.x;
    const int l = tid & 63, w = tid >> 6;
    const int wr = w >> 2, wc = w & 3;            // 2M x 4N waves
    const int lr = l & 15, lk = l >> 4;

    // XCD swizzle over 384 blocks (48 consecutive per XCD), then problem decode
    const int bid = blockIdx.x;
    const int swz = (bid & 7) * 48 + (bid >> 3);
    const int prob = swz >> 7;                    // 0:Q 1:K 2:V
    const int t128 = swz & 127;

    const f16* A; const f16* W; int bm, bn;
    if (prob == 0)      { A = hs; W = Wq; bm = (t128 >> 3) * 256; bn = (t128 & 7) * 256; }
    else if (prob == 1) { A = es; W = Wk; bm = (t128 >> 3) * 256; bn = (t128 & 7) * 256; }
    else                { A = Wv; W = es; bm = (t128 >> 4) * 256; bn = (t128 & 15) * 256; }

    const int srow0 = tid >> 3, sg = tid & 7;

#define STAGEH(dst, src, r0, k0) do {                                                    \
    _Pragma("unroll")                                                                    \
    for (int u = 0; u < 2; ++u) {                                                        \
        const int row = u * 64 + srow0;                                                  \
        const int lg = sg ^ (row & 7);                                                   \
        gl2lds16((src) + (size_t)((r0) + row) * 2048 + (k0) + lg * 8,                    \
                 (dst) + row * 64 + sg * 8);                                             \
    }                                                                                    \
} while (0)

    f32x4 acc[8][4];
#pragma unroll
    for (int m = 0; m < 8; ++m)
#pragma unroll
        for (int n = 0; n < 4; ++n) acc[m][n] = (f32x4){0.f, 0.f, 0.f, 0.f};

    // prologue: all 4 half-tiles of K-tile 0 into buf 0 (8 loads outstanding)
    STAGEH(LA[0][0], A, bm, 0);
    STAGEH(LA[0][1], A, bm + 128, 0);
    STAGEH(LB[0][0], W, bn, 0);
    STAGEH(LB[0][1], W, bn + 128, 0);

    for (int j = 0; j < 32; ++j) {
        const int cur = j & 1;
        const int k1 = (j + 1) * 64;
#pragma unroll
        for (int q = 0; q < 4; ++q) {
            // stage ONE half-tile of tile j+1 into buf cur^1 (safe: buf^1 last read in tile j-1,
            // all waves past that tile's final barrier before entering tile j)
            if (j < 31) {
                if (q == 0)      STAGEH(LA[cur ^ 1][0], A, bm, k1);
                else if (q == 1) STAGEH(LA[cur ^ 1][1], A, bm + 128, k1);
                else if (q == 2) STAGEH(LB[cur ^ 1][0], W, bn, k1);
                else             STAGEH(LB[cur ^ 1][1], W, bn + 128, k1);
            }
            if (q == 0) {
                // wait for tile j's 8 loads (leave the 2 just-issued in flight), then sync
                if (j < 31) asm volatile("s_waitcnt vmcnt(2)" ::: "memory");
                else        asm volatile("s_waitcnt vmcnt(0)" ::: "memory");
                __builtin_amdgcn_s_barrier();
                __builtin_amdgcn_sched_barrier(0);
            }

            // quadrant q: m-half qm, n-half qn -> 12 ds_read_b128 + 16 MFMA
            const int qm = q >> 1, qn = q & 1;
            f16x8 a[4][2], b[2][2];
#pragma unroll
            for (int m = 0; m < 4; ++m) {
                const int row = qm * 64 + m * 16 + lr;
#pragma unroll
                for (int k = 0; k < 2; ++k) {
                    const int dg = k * 4 + lk;
                    a[m][k] = *(const f16x8*)(LA[cur][wr] + row * 64 + (dg ^ (row & 7)) * 8);
                }
            }
#pragma unroll
            for (int n = 0; n < 2; ++n) {
                const int rb = wc * 64 + qn * 32 + n * 16 + lr;
                const int hb = rb >> 7, rh = rb & 127;
#pragma unroll
                for (int k = 0; k < 2; ++k) {
                    const int dg = k * 4 + lk;
                    b[n][k] = *(const f16x8*)(LB[cur][hb] + rh * 64 + (dg ^ (rh & 7)) * 8);
                }
            }
            __builtin_amdgcn_s_setprio(1);
#pragma unroll
            for (int m = 0; m < 4; ++m)
#pragma unroll
                for (int n = 0; n < 2; ++n) {
                    acc[qm * 4 + m][qn * 2 + n] = MFMA16(a[m][0], b[n][0], acc[qm * 4 + m][qn * 2 + n]);
                    acc[qm * 4 + m][qn * 2 + n] = MFMA16(a[m][1], b[n][1], acc[qm * 4 + m][qn * 2 + n]);
                }
            __builtin_amdgcn_s_setprio(0);
            __builtin_amdgcn_s_barrier();
        }
    }
#undef STAGEH

    // epilogue
    const float* Cs = prob == 0 ? cq : ck;
    const float* Sn = prob == 0 ? sq : sk;
    f16* Out = prob == 0 ? Qo : Ko;
#pragma unroll
    for (int m = 0; m < 8; ++m)
#pragma unroll
        for (int n = 0; n < 4; ++n)
#pragma unroll
            for (int jj = 0; jj < 4; ++jj) {
                const int r = bm + wr * 128 + m * 16 + (lk << 2) + jj;
                const int c = bn + wc * 64 + n * 16 + lr;
                const float v = acc[m][n][jj];
                if (prob == 2) {
                    Vo[(size_t)((c >> 11) * 2048 + r) * 2048 + (c & 2047)] = (f16)v;
                } else {
                    const float vp = __shfl_xor(v, 1);
                    const int tt = r & 2047;
                    const int i2 = (c & 127) >> 1;
                    const float co = Cs[tt * 64 + i2];
                    const float si = Sn[tt * 64 + i2];
                    const float y = (c & 1) ? fmaf(v, co, vp * si) : fmaf(v, co, -vp * si);
                    Out[(size_t)r * 2048 + c] = (f16)y;
                }
            }
}

// ---------------- O-GEMM: 128x128 tile m97-structure (proven), f32 out ----------------
__global__ __launch_bounds__(256, 2) void gemm16f(
    const f16* __restrict__ A, const f16* __restrict__ W,
    float* __restrict__ C, int M, int N, int K)
{
    __shared__ __align__(16) f16 Al[128 * 64];
    __shared__ __align__(16) f16 Bl[128 * 64];
    const int tid = threadIdx.x;
    const int l = tid & 63, w = tid >> 6;
    const int wr = w >> 1, wc = w & 1;

    const int nwg = gridDim.x, cpx = nwg >> 3;
    const int bid = blockIdx.x;
    const int swz = (bid & 7) * cpx + (bid >> 3);
    const int nbn = N >> 7;
    const int bm = (swz / nbn) * 128, bn = (swz % nbn) * 128;

    f32x4 acc[4][4];
#pragma unroll
    for (int i = 0; i < 4; ++i)
#pragma unroll
        for (int j = 0; j < 4; ++j) acc[i][j] = (f32x4){0.f, 0.f, 0.f, 0.f};

    const int srow = tid >> 3;
    const int sg = tid & 7;

    for (int k0 = 0; k0 < K; k0 += 64) {
        __syncthreads();
#pragma unroll
        for (int i = 0; i < 4; ++i) {
            const int row = i * 32 + srow;
            const int lg = sg ^ (row & 7);
            gl2lds16(A + (size_t)(bm + row) * K + k0 + lg * 8, Al + row * 64 + sg * 8);
            gl2lds16(W + (size_t)(bn + row) * K + k0 + lg * 8, Bl + row * 64 + sg * 8);
        }
        __syncthreads();
#pragma unroll
        for (int kk = 0; kk < 2; ++kk) {
            f16x8 a[4], b[4];
            const int g = kk * 4 + (l >> 4);
#pragma unroll
            for (int m = 0; m < 4; ++m) {
                const int row = wr * 64 + m * 16 + (l & 15);
                a[m] = *(const f16x8*)(Al + row * 64 + (g ^ (row & 7)) * 8);
            }
#pragma unroll
            for (int n = 0; n < 4; ++n) {
                const int row = wc * 64 + n * 16 + (l & 15);
                b[n] = *(const f16x8*)(Bl + row * 64 + (g ^ (row & 7)) * 8);
            }
#pragma unroll
            for (int m = 0; m < 4; ++m)
#pragma unroll
                for (int n = 0; n < 4; ++n)
                    acc[m][n] = MFMA16(a[m], b[n], acc[m][n]);
        }
    }

#pragma unroll
    for (int m = 0; m < 4; ++m)
#pragma unroll
        for (int n = 0; n < 4; ++n)
#pragma unroll
            for (int j = 0; j < 4; ++j) {
                const int r = bm + wr * 64 + m * 16 + ((l >> 4) << 2) + j;
                const int c = bn + wc * 64 + n * 16 + (l & 15);
                C[(size_t)r * N + c] = acc[m][n][j];
            }
}

// ---------------- Flash attention (round-12 proven): 4 waves x 32 q-rows, single-buf ----------------
__global__ __launch_bounds__(256, 2) void attn16(
    const f16* __restrict__ Qg, const f16* __restrict__ Kg,
    const f16* __restrict__ Vt, f16* __restrict__ Og)
{
    __shared__ __align__(16) f16 Kl[64 * 132];
    __shared__ __align__(16) f16 Vl[128 * 68];
    __shared__ float bnc[4][32];

    const int tid = threadIdx.x;
    const int l = tid & 63, w = tid >> 6;
    const int l31 = l & 31, hi = l >> 5;
    const int hi4 = hi * 4;

    const int krow = tid >> 4, kg = tid & 15;
    const int vd = tid >> 3, vg = tid & 7;

    const int bid = blockIdx.x;
    const int swz = (bid & 7) * 64 + (bid >> 3);
    const int bh = swz >> 4, qt = swz & 15;
    const int b = bh >> 4, h = bh & 15;

    const int qrow = b * 2048 + qt * 128 + w * 32 + l31;
    const f16 qsc = (f16)(0.088388347648318447f * 1.44269504088896f);
    f16x8 qf[8];
#pragma unroll
    for (int kc = 0; kc < 8; ++kc) {
        f16x8 t0 = *(const f16x8*)(Qg + (size_t)qrow * 2048 + h * 128 + kc * 16 + hi * 8);
#pragma unroll
        for (int e = 0; e < 8; ++e) t0[e] = t0[e] * qsc;
        qf[kc] = t0;
    }

    f32x16 o[4] = {Z16, Z16, Z16, Z16};
    float mrow = -3.0e38f, lrow = 0.0f;

    const f16* Kbase = Kg + (size_t)(b * 2048) * 2048 + h * 128;
    const f16* Vbase = Vt + (size_t)(b * 2048 + h * 128) * 2048;

    u32x4 kst[4], vst[4];

#define LOADT(st) do {                                                                   \
    _Pragma("unroll")                                                                    \
    for (int u = 0; u < 4; ++u)                                                          \
        kst[u] = *(const u32x4*)(Kbase + (size_t)((st) + krow + u * 16) * 2048 + kg * 8);\
    _Pragma("unroll")                                                                    \
    for (int u = 0; u < 4; ++u)                                                          \
        vst[u] = *(const u32x4*)(Vbase + (size_t)(vd + u * 32) * 2048 + (st) + vg * 8);  \
} while (0)

#define WRITET() do {                                                                    \
    _Pragma("unroll")                                                                    \
    for (int u = 0; u < 4; ++u) {                                                        \
        f16* p = &Kl[(krow + u * 16) * 132 + kg * 8];                                    \
        *(u32x2*)p       = (u32x2){kst[u].x, kst[u].y};                                  \
        *(u32x2*)(p + 4) = (u32x2){kst[u].z, kst[u].w};                                  \
    }                                                                                    \
    _Pragma("unroll")                                                                    \
    for (int u = 0; u < 4; ++u) {                                                        \
        f16* p = &Vl[(vd + u * 32) * 68 + vg * 8];                                       \
        *(u32x2*)p       = (u32x2){vst[u].x, vst[u].y};                                  \
        *(u32x2*)(p + 4) = (u32x2){vst[u].z, vst[u].w};                                  \
    }                                                                                    \
} while (0)

    LOADT(0);
    WRITET();
    __syncthreads();

    for (int t = 0; t < 32; ++t) {
        if (t < 31) LOADT((t + 1) * 64);

        f32x16 p0 = Z16, p1 = Z16;
        __builtin_amdgcn_s_setprio(1);
#pragma unroll
        for (int kc = 0; kc < 8; ++kc) {
            const int go = (kc * 2 + hi) * 8;
            const f16* kp0 = Kl + l31 * 132 + go;
            const f16* kp1 = Kl + (32 + l31) * 132 + go;
            const f16x4 a0 = *(const f16x4*)kp0, a1 = *(const f16x4*)(kp0 + 4);
            const f16x4 b0 = *(const f16x4*)kp1, b1 = *(const f16x4*)(kp1 + 4);
            const f16x8 k0 = __builtin_shufflevector(a0, a1, 0, 1, 2, 3, 4, 5, 6, 7);
            const f16x8 k1 = __builtin_shufflevector(b0, b1, 0, 1, 2, 3, 4, 5, 6, 7);
            p0 = MFMA32(k0, qf[kc], p0);
            p1 = MFMA32(k1, qf[kc], p1);
        }
        __builtin_amdgcn_s_setprio(0);

        float pp[32];
#pragma unroll
        for (int r = 0; r < 16; ++r) { pp[r] = p0[r]; pp[16 + r] = p1[r]; }
        float mv[11];
#pragma unroll
        for (int i = 0; i < 10; ++i) mv[i] = MAX3(pp[3 * i], pp[3 * i + 1], pp[3 * i + 2]);
        mv[10] = fmaxf(pp[30], pp[31]);
        const float n0 = MAX3(mv[0], mv[1], mv[2]);
        const float n1 = MAX3(mv[3], mv[4], mv[5]);
        const float n2 = MAX3(mv[6], mv[7], mv[8]);
        const float n3 = MAX3(mv[9], mv[10], n0);
        float mx = MAX3(n1, n2, n3);
        mx = fswapmax(mx);

        if (!__all(mx <= mrow + 8.0f)) {
            const float mn = fmaxf(mrow, mx);
            const float cr = EX2(mrow - mn);
            mrow = mn;
            lrow *= cr;
            if (hi == 0) bnc[w][l31] = cr;
#pragma unroll
            for (int r = 0; r < 16; ++r) {
                const float crr = bnc[w][(r & 3) + 8 * (r >> 2) + 4 * hi];
                o[0][r] *= crr; o[1][r] *= crr; o[2][r] *= crr; o[3][r] *= crr;
            }
        }

        float st16[16];
#pragma unroll
        for (int r = 0; r < 16; ++r) {
            p0[r] = EX2(p0[r] - mrow);
            p1[r] = EX2(p1[r] - mrow);
            st16[r] = p0[r] + p1[r];
        }
#pragma unroll
        for (int r = 0; r < 8; ++r) st16[r] += st16[r + 8];
#pragma unroll
        for (int r = 0; r < 4; ++r) st16[r] += st16[r + 4];
        lrow += fswapsum((st16[0] + st16[1]) + (st16[2] + st16[3]));

        f16x8 pf[4];
#pragma unroll
        for (int ksl = 0; ksl < 2; ++ksl) {
            u32x4 w0 = {pkz(p0[8*ksl+0], p0[8*ksl+1]), pkz(p0[8*ksl+2], p0[8*ksl+3]),
                        pkz(p0[8*ksl+4], p0[8*ksl+5]), pkz(p0[8*ksl+6], p0[8*ksl+7])};
            pf[ksl] = __builtin_bit_cast(f16x8, w0);
            u32x4 w1 = {pkz(p1[8*ksl+0], p1[8*ksl+1]), pkz(p1[8*ksl+2], p1[8*ksl+3]),
                        pkz(p1[8*ksl+4], p1[8*ksl+5]), pkz(p1[8*ksl+6], p1[8*ksl+7])};
            pf[2 + ksl] = __builtin_bit_cast(f16x8, w1);
        }

        __builtin_amdgcn_s_setprio(1);
#pragma unroll
        for (int dt = 0; dt < 4; ++dt) {
            const f16* vrow = Vl + (dt * 32 + l31) * 68;
#pragma unroll
            for (int ks = 0; ks < 4; ++ks) {
                const f16x4 vlo = *(const f16x4*)(vrow + ks * 16 + hi4);
                const f16x4 vhi = *(const f16x4*)(vrow + ks * 16 + hi4 + 8);
                const f16x8 vf = __builtin_shufflevector(vlo, vhi, 0, 1, 2, 3, 4, 5, 6, 7);
                o[dt] = MFMA32(pf[ks], vf, o[dt]);
            }
        }
        __builtin_amdgcn_s_setprio(0);

        __syncthreads();
        if (t < 31) {
            WRITET();
            __syncthreads();
        }
    }
#undef LOADT
#undef WRITET

    const float inv = 1.0f / lrow;
    if (hi == 0) bnc[w][l31] = inv;
#pragma unroll
    for (int r = 0; r < 16; ++r) {
        const int qq = (r & 3) + 8 * (r >> 2) + 4 * hi;
        const float ir = bnc[w][qq];
        const size_t row = (size_t)(b * 2048 + qt * 128 + w * 32 + qq);
#pragma unroll
        for (int dt = 0; dt < 4; ++dt)
            Og[row * 2048 + h * 128 + dt * 32 + l31] = (f16)(o[dt][r] * ir);
    }
}

extern "C" void kernel_launch(void* const* d_in, const int* in_sizes, int n_in,
                              void* d_out, int out_size, void* d_ws, size_t ws_size,
                              hipStream_t stream) {
    const float* hs = (const float*)d_in[0];
    const float* es = (const float*)d_in[1];
    const float* Wq = (const float*)d_in[2];
    const float* Wk = (const float*)d_in[3];
    const float* Wv = (const float*)d_in[4];
    const float* Wo = (const float*)d_in[5];
    const float* cq = (const float*)d_in[6];
    const float* sq = (const float*)d_in[7];
    const float* ck = (const float*)d_in[8];
    const float* sk = (const float*)d_in[9];
    float* out = (float*)d_out;

    f16* hs16 = (f16*)d_ws;
    f16* es16 = hs16 + 8388608;
    f16* Wq16 = es16 + 8388608;
    f16* Wk16 = Wq16 + 4194304;
    f16* Wv16 = Wk16 + 4194304;
    f16* Wo16 = Wv16 + 4194304;
    f16* Q16  = Wo16 + 4194304;
    f16* K16  = Q16 + 8388608;
    f16* Vt16 = K16 + 8388608;
    f16* ctx16 = hs16;   // reuse (hs16 dead after qkv256)

    const dim3 tB(256);
    cvt_all<<<dim3(16384), tB, 0, stream>>>(hs, es, Wq, Wk, Wv, Wo, hs16);

    qkv256<<<dim3(384), dim3(512), 0, stream>>>(hs16, es16, Wq16, Wk16, Wv16,
                                                Q16, K16, Vt16, cq, sq, ck, sk);

    attn16<<<dim3(512), tB, 0, stream>>>(Q16, K16, Vt16, ctx16);

    gemm16f<<<dim3(512), tB, 0, stream>>>(ctx16, Wo16, out, 4096, 2048, 2048);
}

// Round 15
// 286.784 us; speedup vs baseline: 1.3615x; 1.3615x over previous
//
#include <hip/hip_runtime.h>
#include <cmath>

typedef _Float16 f16;
typedef _Float16 f16x8 __attribute__((ext_vector_type(8)));
typedef _Float16 f16x4 __attribute__((ext_vector_type(4)));
typedef __fp16 fp16x2 __attribute__((ext_vector_type(2)));
typedef float f32x4 __attribute__((ext_vector_type(4)));
typedef float f32x16 __attribute__((ext_vector_type(16)));
typedef unsigned int u32;
typedef unsigned int u32x2 __attribute__((ext_vector_type(2)));
typedef unsigned int u32x4 __attribute__((ext_vector_type(4)));

#define MFMA16(a, b, c) __builtin_amdgcn_mfma_f32_16x16x32_f16(a, b, c, 0, 0, 0)
#define MFMA32(a, b, c) __builtin_amdgcn_mfma_f32_32x32x16_f16(a, b, c, 0, 0, 0)
#define Z16 ((f32x16){0.f,0.f,0.f,0.f,0.f,0.f,0.f,0.f,0.f,0.f,0.f,0.f,0.f,0.f,0.f,0.f})
#define EX2(x) __builtin_amdgcn_exp2f(x)

__device__ __forceinline__ void gl2lds16(const f16* g, f16* l) {
    __builtin_amdgcn_global_load_lds(
        (const __attribute__((address_space(1))) unsigned int*)g,
        (__attribute__((address_space(3))) unsigned int*)l, 16, 0, 0);
}

__device__ __forceinline__ u32 pkz(float x, float y) {
    fp16x2 h = __builtin_amdgcn_cvt_pkrtz(x, y);
    return __builtin_bit_cast(u32, h);
}
// own + partner(lane^32): explicit fresh register (=&v) so operands can't coalesce;
// symmetric combine -> correct under either permlane32_swap direction.
__device__ __forceinline__ float fswapsum(float x) {
    u32 a = __builtin_bit_cast(u32, x), b;
    asm volatile("v_mov_b32 %0, %1" : "=&v"(b) : "v"(a));
    asm volatile("v_permlane32_swap_b32 %0, %1" : "+v"(a), "+v"(b));
    return __builtin_bit_cast(float, a) + __builtin_bit_cast(float, b);
}
__device__ __forceinline__ float fswapmax(float x) {
    u32 a = __builtin_bit_cast(u32, x), b;
    asm volatile("v_mov_b32 %0, %1" : "=&v"(b) : "v"(a));
    asm volatile("v_permlane32_swap_b32 %0, %1" : "+v"(a), "+v"(b));
    return fmaxf(__builtin_bit_cast(float, a), __builtin_bit_cast(float, b));
}
#define MAX3(a, b, c) fmaxf(fmaxf((a), (b)), (c))

// ---------------- merged f32 -> f16 convert for all 6 inputs ----------------
__global__ __launch_bounds__(256) void cvt_all(
    const float* __restrict__ hs, const float* __restrict__ es,
    const float* __restrict__ Wq, const float* __restrict__ Wk,
    const float* __restrict__ Wv, const float* __restrict__ Wo,
    f16* __restrict__ dst)
{
    const int c = blockIdx.x * 256 + threadIdx.x;
    const float* src; int off;
    if (c < 2097152) { src = (c < 1048576) ? hs : es; off = c & 1048575; }
    else {
        const int cc = c - 2097152;
        const int wsel = cc >> 19; off = cc & 524287;
        src = wsel == 0 ? Wq : wsel == 1 ? Wk : wsel == 2 ? Wv : Wo;
    }
    const float4* p = (const float4*)src + (size_t)off * 2;
    const float4 a = p[0], b2 = p[1];
    f16x8 o = {(f16)a.x, (f16)a.y, (f16)a.z, (f16)a.w,
               (f16)b2.x, (f16)b2.y, (f16)b2.z, (f16)b2.w};
    *(f16x8*)(dst + (size_t)c * 8) = o;
}

// ---------------- fused Q+K+V projection: 1536 blocks of the PROVEN 128x128 body ----------------
// swz in [0,512): Q = hs@Wq^T + RoPE; [512,1024): K = es@Wk^T + RoPE;
// [1024,1536): V^T = Wv@es^T (transposed write). One dispatch keeps all CUs fed
// across the three problems (no inter-dispatch drain).
__global__ __launch_bounds__(256, 2) void qkv128(
    const f16* __restrict__ hs, const f16* __restrict__ es,
    const f16* __restrict__ Wq, const f16* __restrict__ Wk, const f16* __restrict__ Wv,
    f16* __restrict__ Qo, f16* __restrict__ Ko, f16* __restrict__ Vo,
    const float* __restrict__ cq, const float* __restrict__ sq,
    const float* __restrict__ ck, const float* __restrict__ sk)
{
    __shared__ __align__(16) f16 Al[128 * 64];
    __shared__ __align__(16) f16 Bl[128 * 64];
    const int tid = threadIdx.x;
    const int l = tid & 63, w = tid >> 6;
    const int wr = w >> 1, wc = w & 1;

    // XCD swizzle over 1536 blocks (192 consecutive per XCD)
    const int bid = blockIdx.x;
    const int swz = (bid & 7) * 192 + (bid >> 3);
    const int prob = swz >> 9;          // 0:Q 1:K 2:V
    const int t = swz & 511;

    const f16* A; const f16* W; int bm, bn;
    if (prob == 0)      { A = hs; W = Wq; bm = (t >> 4) * 128; bn = (t & 15) * 128; }
    else if (prob == 1) { A = es; W = Wk; bm = (t >> 4) * 128; bn = (t & 15) * 128; }
    else                { A = Wv; W = es; bm = (t >> 5) * 128; bn = (t & 31) * 128; }

    f32x4 acc[4][4];
#pragma unroll
    for (int i = 0; i < 4; ++i)
#pragma unroll
        for (int j = 0; j < 4; ++j) acc[i][j] = (f32x4){0.f, 0.f, 0.f, 0.f};

    const int srow = tid >> 3;
    const int sg = tid & 7;

    for (int k0 = 0; k0 < 2048; k0 += 64) {
        __syncthreads();
#pragma unroll
        for (int i = 0; i < 4; ++i) {
            const int row = i * 32 + srow;
            const int lg = sg ^ (row & 7);
            gl2lds16(A + (size_t)(bm + row) * 2048 + k0 + lg * 8, Al + row * 64 + sg * 8);
            gl2lds16(W + (size_t)(bn + row) * 2048 + k0 + lg * 8, Bl + row * 64 + sg * 8);
        }
        __syncthreads();
#pragma unroll
        for (int kk = 0; kk < 2; ++kk) {
            f16x8 a[4], b[4];
            const int g = kk * 4 + (l >> 4);
#pragma unroll
            for (int m = 0; m < 4; ++m) {
                const int row = wr * 64 + m * 16 + (l & 15);
                a[m] = *(const f16x8*)(Al + row * 64 + (g ^ (row & 7)) * 8);
            }
#pragma unroll
            for (int n = 0; n < 4; ++n) {
                const int row = wc * 64 + n * 16 + (l & 15);
                b[n] = *(const f16x8*)(Bl + row * 64 + (g ^ (row & 7)) * 8);
            }
#pragma unroll
            for (int m = 0; m < 4; ++m)
#pragma unroll
                for (int n = 0; n < 4; ++n)
                    acc[m][n] = MFMA16(a[m], b[n], acc[m][n]);
        }
    }

    const float* Cs = prob == 0 ? cq : ck;
    const float* Sn = prob == 0 ? sq : sk;
    f16* Out = prob == 0 ? Qo : Ko;
#pragma unroll
    for (int m = 0; m < 4; ++m)
#pragma unroll
        for (int n = 0; n < 4; ++n)
#pragma unroll
            for (int j = 0; j < 4; ++j) {
                const int r = bm + wr * 64 + m * 16 + ((l >> 4) << 2) + j;
                const int c = bn + wc * 64 + n * 16 + (l & 15);
                const float v = acc[m][n][j];
                if (prob == 2) {
                    Vo[(size_t)((c >> 11) * 2048 + r) * 2048 + (c & 2047)] = (f16)v;
                } else {
                    const float vp = __shfl_xor(v, 1);
                    const int tt = r & 2047;
                    const int i2 = (c & 127) >> 1;
                    const float co = Cs[tt * 64 + i2];
                    const float si = Sn[tt * 64 + i2];
                    const float y = (c & 1) ? fmaf(v, co, vp * si) : fmaf(v, co, -vp * si);
                    Out[(size_t)r * 2048 + c] = (f16)y;
                }
            }
}

// ---------------- O-GEMM: 128x128 tile m97-structure (proven), f32 out ----------------
__global__ __launch_bounds__(256, 2) void gemm16f(
    const f16* __restrict__ A, const f16* __restrict__ W,
    float* __restrict__ C, int M, int N, int K)
{
    __shared__ __align__(16) f16 Al[128 * 64];
    __shared__ __align__(16) f16 Bl[128 * 64];
    const int tid = threadIdx.x;
    const int l = tid & 63, w = tid >> 6;
    const int wr = w >> 1, wc = w & 1;

    const int nwg = gridDim.x, cpx = nwg >> 3;
    const int bid = blockIdx.x;
    const int swz = (bid & 7) * cpx + (bid >> 3);
    const int nbn = N >> 7;
    const int bm = (swz / nbn) * 128, bn = (swz % nbn) * 128;

    f32x4 acc[4][4];
#pragma unroll
    for (int i = 0; i < 4; ++i)
#pragma unroll
        for (int j = 0; j < 4; ++j) acc[i][j] = (f32x4){0.f, 0.f, 0.f, 0.f};

    const int srow = tid >> 3;
    const int sg = tid & 7;

    for (int k0 = 0; k0 < K; k0 += 64) {
        __syncthreads();
#pragma unroll
        for (int i = 0; i < 4; ++i) {
            const int row = i * 32 + srow;
            const int lg = sg ^ (row & 7);
            gl2lds16(A + (size_t)(bm + row) * K + k0 + lg * 8, Al + row * 64 + sg * 8);
            gl2lds16(W + (size_t)(bn + row) * K + k0 + lg * 8, Bl + row * 64 + sg * 8);
        }
        __syncthreads();
#pragma unroll
        for (int kk = 0; kk < 2; ++kk) {
            f16x8 a[4], b[4];
            const int g = kk * 4 + (l >> 4);
#pragma unroll
            for (int m = 0; m < 4; ++m) {
                const int row = wr * 64 + m * 16 + (l & 15);
                a[m] = *(const f16x8*)(Al + row * 64 + (g ^ (row & 7)) * 8);
            }
#pragma unroll
            for (int n = 0; n < 4; ++n) {
                const int row = wc * 64 + n * 16 + (l & 15);
                b[n] = *(const f16x8*)(Bl + row * 64 + (g ^ (row & 7)) * 8);
            }
#pragma unroll
            for (int m = 0; m < 4; ++m)
#pragma unroll
                for (int n = 0; n < 4; ++n)
                    acc[m][n] = MFMA16(a[m], b[n], acc[m][n]);
        }
    }

#pragma unroll
    for (int m = 0; m < 4; ++m)
#pragma unroll
        for (int n = 0; n < 4; ++n)
#pragma unroll
            for (int j = 0; j < 4; ++j) {
                const int r = bm + wr * 64 + m * 16 + ((l >> 4) << 2) + j;
                const int c = bn + wc * 64 + n * 16 + (l & 15);
                C[(size_t)r * N + c] = acc[m][n][j];
            }
}

// ---------------- Flash attention (round-12 proven): 4 waves x 32 q-rows, single-buf ----------------
__global__ __launch_bounds__(256, 2) void attn16(
    const f16* __restrict__ Qg, const f16* __restrict__ Kg,
    const f16* __restrict__ Vt, f16* __restrict__ Og)
{
    __shared__ __align__(16) f16 Kl[64 * 132];
    __shared__ __align__(16) f16 Vl[128 * 68];
    __shared__ float bnc[4][32];

    const int tid = threadIdx.x;
    const int l = tid & 63, w = tid >> 6;
    const int l31 = l & 31, hi = l >> 5;
    const int hi4 = hi * 4;

    const int krow = tid >> 4, kg = tid & 15;
    const int vd = tid >> 3, vg = tid & 7;

    const int bid = blockIdx.x;
    const int swz = (bid & 7) * 64 + (bid >> 3);
    const int bh = swz >> 4, qt = swz & 15;
    const int b = bh >> 4, h = bh & 15;

    const int qrow = b * 2048 + qt * 128 + w * 32 + l31;
    const f16 qsc = (f16)(0.088388347648318447f * 1.44269504088896f);
    f16x8 qf[8];
#pragma unroll
    for (int kc = 0; kc < 8; ++kc) {
        f16x8 t0 = *(const f16x8*)(Qg + (size_t)qrow * 2048 + h * 128 + kc * 16 + hi * 8);
#pragma unroll
        for (int e = 0; e < 8; ++e) t0[e] = t0[e] * qsc;
        qf[kc] = t0;
    }

    f32x16 o[4] = {Z16, Z16, Z16, Z16};
    float mrow = -3.0e38f, lrow = 0.0f;

    const f16* Kbase = Kg + (size_t)(b * 2048) * 2048 + h * 128;
    const f16* Vbase = Vt + (size_t)(b * 2048 + h * 128) * 2048;

    u32x4 kst[4], vst[4];

#define LOADT(st) do {                                                                   \
    _Pragma("unroll")                                                                    \
    for (int u = 0; u < 4; ++u)                                                          \
        kst[u] = *(const u32x4*)(Kbase + (size_t)((st) + krow + u * 16) * 2048 + kg * 8);\
    _Pragma("unroll")                                                                    \
    for (int u = 0; u < 4; ++u)                                                          \
        vst[u] = *(const u32x4*)(Vbase + (size_t)(vd + u * 32) * 2048 + (st) + vg * 8);  \
} while (0)

#define WRITET() do {                                                                    \
    _Pragma("unroll")                                                                    \
    for (int u = 0; u < 4; ++u) {                                                        \
        f16* p = &Kl[(krow + u * 16) * 132 + kg * 8];                                    \
        *(u32x2*)p       = (u32x2){kst[u].x, kst[u].y};                                  \
        *(u32x2*)(p + 4) = (u32x2){kst[u].z, kst[u].w};                                  \
    }                                                                                    \
    _Pragma("unroll")                                                                    \
    for (int u = 0; u < 4; ++u) {                                                        \
        f16* p = &Vl[(vd + u * 32) * 68 + vg * 8];                                       \
        *(u32x2*)p       = (u32x2){vst[u].x, vst[u].y};                                  \
        *(u32x2*)(p + 4) = (u32x2){vst[u].z, vst[u].w};                                  \
    }                                                                                    \
} while (0)

    LOADT(0);
    WRITET();
    __syncthreads();

    for (int t = 0; t < 32; ++t) {
        if (t < 31) LOADT((t + 1) * 64);

        f32x16 p0 = Z16, p1 = Z16;
        __builtin_amdgcn_s_setprio(1);
#pragma unroll
        for (int kc = 0; kc < 8; ++kc) {
            const int go = (kc * 2 + hi) * 8;
            const f16* kp0 = Kl + l31 * 132 + go;
            const f16* kp1 = Kl + (32 + l31) * 132 + go;
            const f16x4 a0 = *(const f16x4*)kp0, a1 = *(const f16x4*)(kp0 + 4);
            const f16x4 b0 = *(const f16x4*)kp1, b1 = *(const f16x4*)(kp1 + 4);
            const f16x8 k0 = __builtin_shufflevector(a0, a1, 0, 1, 2, 3, 4, 5, 6, 7);
            const f16x8 k1 = __builtin_shufflevector(b0, b1, 0, 1, 2, 3, 4, 5, 6, 7);
            p0 = MFMA32(k0, qf[kc], p0);
            p1 = MFMA32(k1, qf[kc], p1);
        }
        __builtin_amdgcn_s_setprio(0);

        float pp[32];
#pragma unroll
        for (int r = 0; r < 16; ++r) { pp[r] = p0[r]; pp[16 + r] = p1[r]; }
        float mv[11];
#pragma unroll
        for (int i = 0; i < 10; ++i) mv[i] = MAX3(pp[3 * i], pp[3 * i + 1], pp[3 * i + 2]);
        mv[10] = fmaxf(pp[30], pp[31]);
        const float n0 = MAX3(mv[0], mv[1], mv[2]);
        const float n1 = MAX3(mv[3], mv[4], mv[5]);
        const float n2 = MAX3(mv[6], mv[7], mv[8]);
        const float n3 = MAX3(mv[9], mv[10], n0);
        float mx = MAX3(n1, n2, n3);
        mx = fswapmax(mx);

        if (!__all(mx <= mrow + 8.0f)) {
            const float mn = fmaxf(mrow, mx);
            const float cr = EX2(mrow - mn);
            mrow = mn;
            lrow *= cr;
            if (hi == 0) bnc[w][l31] = cr;
#pragma unroll
            for (int r = 0; r < 16; ++r) {
                const float crr = bnc[w][(r & 3) + 8 * (r >> 2) + 4 * hi];
                o[0][r] *= crr; o[1][r] *= crr; o[2][r] *= crr; o[3][r] *= crr;
            }
        }

        float st16[16];
#pragma unroll
        for (int r = 0; r < 16; ++r) {
            p0[r] = EX2(p0[r] - mrow);
            p1[r] = EX2(p1[r] - mrow);
            st16[r] = p0[r] + p1[r];
        }
#pragma unroll
        for (int r = 0; r < 8; ++r) st16[r] += st16[r + 8];
#pragma unroll
        for (int r = 0; r < 4; ++r) st16[r] += st16[r + 4];
        lrow += fswapsum((st16[0] + st16[1]) + (st16[2] + st16[3]));

        f16x8 pf[4];
#pragma unroll
        for (int ksl = 0; ksl < 2; ++ksl) {
            u32x4 w0 = {pkz(p0[8*ksl+0], p0[8*ksl+1]), pkz(p0[8*ksl+2], p0[8*ksl+3]),
                        pkz(p0[8*ksl+4], p0[8*ksl+5]), pkz(p0[8*ksl+6], p0[8*ksl+7])};
            pf[ksl] = __builtin_bit_cast(f16x8, w0);
            u32x4 w1 = {pkz(p1[8*ksl+0], p1[8*ksl+1]), pkz(p1[8*ksl+2], p1[8*ksl+3]),
                        pkz(p1[8*ksl+4], p1[8*ksl+5]), pkz(p1[8*ksl+6], p1[8*ksl+7])};
            pf[2 + ksl] = __builtin_bit_cast(f16x8, w1);
        }

        __builtin_amdgcn_s_setprio(1);
#pragma unroll
        for (int dt = 0; dt < 4; ++dt) {
            const f16* vrow = Vl + (dt * 32 + l31) * 68;
#pragma unroll
            for (int ks = 0; ks < 4; ++ks) {
                const f16x4 vlo = *(const f16x4*)(vrow + ks * 16 + hi4);
                const f16x4 vhi = *(const f16x4*)(vrow + ks * 16 + hi4 + 8);
                const f16x8 vf = __builtin_shufflevector(vlo, vhi, 0, 1, 2, 3, 4, 5, 6, 7);
                o[dt] = MFMA32(pf[ks], vf, o[dt]);
            }
        }
        __builtin_amdgcn_s_setprio(0);

        __syncthreads();
        if (t < 31) {
            WRITET();
            __syncthreads();
        }
    }
#undef LOADT
#undef WRITET

    const float inv = 1.0f / lrow;
    if (hi == 0) bnc[w][l31] = inv;
#pragma unroll
    for (int r = 0; r < 16; ++r) {
        const int qq = (r & 3) + 8 * (r >> 2) + 4 * hi;
        const float ir = bnc[w][qq];
        const size_t row = (size_t)(b * 2048 + qt * 128 + w * 32 + qq);
#pragma unroll
        for (int dt = 0; dt < 4; ++dt)
            Og[row * 2048 + h * 128 + dt * 32 + l31] = (f16)(o[dt][r] * ir);
    }
}

extern "C" void kernel_launch(void* const* d_in, const int* in_sizes, int n_in,
                              void* d_out, int out_size, void* d_ws, size_t ws_size,
                              hipStream_t stream) {
    const float* hs = (const float*)d_in[0];
    const float* es = (const float*)d_in[1];
    const float* Wq = (const float*)d_in[2];
    const float* Wk = (const float*)d_in[3];
    const float* Wv = (const float*)d_in[4];
    const float* Wo = (const float*)d_in[5];
    const float* cq = (const float*)d_in[6];
    const float* sq = (const float*)d_in[7];
    const float* ck = (const float*)d_in[8];
    const float* sk = (const float*)d_in[9];
    float* out = (float*)d_out;

    f16* hs16 = (f16*)d_ws;
    f16* es16 = hs16 + 8388608;
    f16* Wq16 = es16 + 8388608;
    f16* Wk16 = Wq16 + 4194304;
    f16* Wv16 = Wk16 + 4194304;
    f16* Wo16 = Wv16 + 4194304;
    f16* Q16  = Wo16 + 4194304;
    f16* K16  = Q16 + 8388608;
    f16* Vt16 = K16 + 8388608;
    f16* ctx16 = hs16;   // reuse (hs16 dead after qkv128)

    const dim3 tB(256);
    cvt_all<<<dim3(16384), tB, 0, stream>>>(hs, es, Wq, Wk, Wv, Wo, hs16);

    qkv128<<<dim3(1536), tB, 0, stream>>>(hs16, es16, Wq16, Wk16, Wv16,
                                          Q16, K16, Vt16, cq, sq, ck, sk);

    attn16<<<dim3(512), tB, 0, stream>>>(Q16, K16, Vt16, ctx16);

    gemm16f<<<dim3(512), tB, 0, stream>>>(ctx16, Wo16, out, 4096, 2048, 2048);
}